// Round 1
// baseline (1683.660 us; speedup 1.0000x reference)
//
#include <hip/hip_runtime.h>

typedef __attribute__((ext_vector_type(4))) float  f32x4;
typedef __attribute__((ext_vector_type(8))) float  f32x8;
typedef __attribute__((ext_vector_type(8))) __bf16 bf16x8;
typedef __attribute__((ext_vector_type(4))) __bf16 bf16x4;
typedef unsigned short u16;

constexpr int NN = 16384;    // nodes
constexpr int HH = 256;      // hidden
constexpr int NE = 1048576;  // edges

// ---- workspace layout (bytes, all 256-aligned) ----
constexpr size_t WS_W1SW  = 0;                              // 8 MB  swizzled bf16 W1
constexpr size_t WS_W2SW  = WS_W1SW + (size_t)NN*HH*2;      // 128 KB swizzled bf16 W2
constexpr size_t WS_H1PRE = WS_W2SW + (size_t)HH*HH*2;      // 8 MB  bf16 x@W1
constexpr size_t WS_H1    = WS_H1PRE + (size_t)NN*HH*2;     // 8 MB  bf16 layer1 out
constexpr size_t WS_H2PRE = WS_H1 + (size_t)NN*HH*2;        // 8 MB  bf16 h1@W2
constexpr size_t WS_H2    = WS_H2PRE + (size_t)NN*HH*2;     // 8 MB  bf16 layer2 out
constexpr size_t WS_DEG   = WS_H2 + (size_t)NN*HH*2;        // 64 KB
constexpr size_t WS_OFFS  = WS_DEG + (size_t)NN*4;          // 64 KB + pad (NN+64 ints)
constexpr size_t WS_CURS  = WS_OFFS + (size_t)(NN+64)*4;
constexpr size_t WS_DINV  = WS_CURS + (size_t)NN*4;
constexpr size_t WS_P     = WS_DINV + (size_t)NN*4;
constexpr size_t WS_Q     = WS_P + (size_t)NN*4;
constexpr size_t WS_CSR   = WS_Q + (size_t)NN*4;            // 4 MB
constexpr size_t WS_PART  = WS_CSR + (size_t)NE*4;          // splitk * 16 MB fp32 partials

__device__ inline u16 f2bf(float f) { __bf16 b = (__bf16)f; return __builtin_bit_cast(u16, b); }

__device__ inline void load_lds16(const void* g, void* l) {
  __builtin_amdgcn_global_load_lds((const __attribute__((address_space(1))) void*)g,
                                   (__attribute__((address_space(3))) void*)l, 16, 0, 0);
}

// ---------------- CSR build ----------------
__global__ void k_zero(int* __restrict__ a, int n) {
  int i = blockIdx.x * blockDim.x + threadIdx.x;
  if (i < n) a[i] = 0;
}

__global__ void k_hist(const int* __restrict__ dst, int* __restrict__ deg) {
  int e = blockIdx.x * blockDim.x + threadIdx.x;
  if (e < NE) atomicAdd(&deg[dst[e]], 1);
}

__global__ void k_scan(const int* __restrict__ deg, int* __restrict__ offs, float* __restrict__ dinv) {
  __shared__ int sums[1024];
  int t = threadIdx.x;
  int base = t * 16;
  int local[16]; int s = 0;
  for (int i = 0; i < 16; ++i) {
    local[i] = s;
    int d = deg[base + i];
    s += d;
    dinv[base + i] = rsqrtf((float)(d + 1));   // +1 self-loop; deg>0 always
  }
  sums[t] = s;
  __syncthreads();
  for (int off = 1; off < 1024; off <<= 1) {
    int v = (t >= off) ? sums[t - off] : 0;
    __syncthreads();
    if (t >= off) sums[t] += v;
    __syncthreads();
  }
  int prefix = (t > 0) ? sums[t - 1] : 0;
  for (int i = 0; i < 16; ++i) offs[base + i] = prefix + local[i];
  if (t == 1023) offs[NN] = sums[1023];
}

__global__ void k_scatter(const int* __restrict__ src, const int* __restrict__ dst,
                          const int* __restrict__ offs, int* __restrict__ curs, int* __restrict__ csr) {
  int e = blockIdx.x * blockDim.x + threadIdx.x;
  if (e < NE) {
    int d = dst[e];
    int pos = atomicAdd(&curs[d], 1);
    csr[offs[d] + pos] = src[e];
  }
}

// ---------------- W swizzle (fp32 [K][256] -> bf16 MFMA-chunk order) ----------------
// chunk linear (per 32-k block): ((n>>4)*4 + (k>>3)&3)*16 + (n&15), 8 consecutive k inside.
__global__ void k_swizzleW(const float* __restrict__ W, u16* __restrict__ out, int K) {
  int o = blockIdx.x * blockDim.x + threadIdx.x;
  if (o >= K * 256) return;
  int j  = o & 7;
  int ml = (o >> 3) & 15;
  int kg = (o >> 7) & 3;
  int st = (o >> 9) & 15;
  int kb = o >> 13;
  int n = st * 16 + ml;
  int k = (kb << 5) + (kg << 3) + j;
  out[o] = f2bf(W[(size_t)k * 256 + n]);
}

// ---------------- GEMM: C[M,256] = A[M,K] @ Bsw ----------------
// BM x 256 tile, BK=32, waves as (NTHR/256) x 4, each wave 64x64 via 4x4 mfma_f32_16x16x32_bf16.
// LDS chunk layout: fragment reads are ds_read_b128 at (subtile*1024 + lane*16) -> conflict-free.
template<int BM, int NTHR, bool CONV, bool PART>
__global__ __launch_bounds__(NTHR, 4)
void k_gemm(const float* __restrict__ Af, const u16* __restrict__ Ab,
            const u16* __restrict__ Bsw, float* __restrict__ Cp, u16* __restrict__ Cb,
            int K, int ksh)
{
  __shared__ __align__(16) u16 ldsA[BM * 32];
  __shared__ __align__(16) u16 ldsB[256 * 32];

  int id = blockIdx.x;
  int y  = id & ((1 << ksh) - 1);    // split-K slice; = XCD&(splitk-1) under round-robin dispatch
  int x  = id >> ksh;
  int m0 = x * BM;
  int nkb = (K >> 5) >> ksh;
  int kb0 = y * nkb;

  int tid = threadIdx.x, lane = tid & 63, wave = tid >> 6;
  int wm = wave >> 2, wn = wave & 3;

  f32x4 acc[4][4] = {};

  // A staging: one 16B chunk per thread per K-step (chunks == NTHR by construction)
  int am  = ((tid >> 6) << 4) + (tid & 15);
  int akg = (tid >> 4) & 3;
  const float* ap  = nullptr;
  const u16*   apb = nullptr;
  if constexpr (CONV) ap  = Af + (size_t)(m0 + am) * K + (akg << 3) + ((size_t)kb0 << 5);
  else                apb = Ab + (size_t)(m0 + am) * K + (akg << 3) + ((size_t)kb0 << 5);
  u16* ldsAw = ldsA + tid * 8;
  const u16* bbase = Bsw + (size_t)kb0 * 8192;

  for (int kb = 0; kb < nkb; ++kb) {
    __syncthreads();
    const u16* bsrc = bbase + (size_t)kb * 8192;
    constexpr int BITER = 1024 / NTHR;
#pragma unroll
    for (int i = 0; i < BITER; ++i) {
      int c = tid + i * NTHR;
      load_lds16(bsrc + c * 8, ldsB + c * 8);
    }
    if constexpr (CONV) {
      f32x8 v = *(const f32x8*)ap;
      bf16x8 w = __builtin_convertvector(v, bf16x8);
      *(bf16x8*)ldsAw = w;
      ap += 32;
    } else {
      bf16x8 w = *(const bf16x8*)apb;
      *(bf16x8*)ldsAw = w;
      apb += 32;
    }
    __syncthreads();

    bf16x8 afr[4], bfr[4];
#pragma unroll
    for (int f = 0; f < 4; ++f)
      afr[f] = *(const bf16x8*)(ldsA + ((wm * 4 + f) * 64 + lane) * 8);
#pragma unroll
    for (int f = 0; f < 4; ++f)
      bfr[f] = *(const bf16x8*)(ldsB + ((wn * 4 + f) * 64 + lane) * 8);
#pragma unroll
    for (int i = 0; i < 4; ++i)
#pragma unroll
      for (int j = 0; j < 4; ++j)
        acc[i][j] = __builtin_amdgcn_mfma_f32_16x16x32_bf16(afr[i], bfr[j], acc[i][j], 0, 0, 0);
  }

  // epilogue: C/D layout col=lane&15, row=(lane>>4)*4+r  [m89-verified]
  int r0 = (lane >> 4) << 2, cc = lane & 15;
  float* cp = nullptr;
  if constexpr (PART) cp = Cp + (size_t)y * NN * HH;
#pragma unroll
  for (int i = 0; i < 4; ++i) {
    int row = m0 + wm * 64 + i * 16 + r0;
#pragma unroll
    for (int j = 0; j < 4; ++j) {
      int col = wn * 64 + j * 16 + cc;
#pragma unroll
      for (int r = 0; r < 4; ++r) {
        if constexpr (PART) cp[(size_t)(row + r) * 256 + col] = acc[i][j][r];
        else                Cb[(size_t)(row + r) * 256 + col] = f2bf(acc[i][j][r]);
      }
    }
  }
}

// ---------------- split-K reduce + bf16 convert ----------------
__global__ void k_reduce(const float* __restrict__ part, u16* __restrict__ out, int splitk) {
  int i = blockIdx.x * blockDim.x + threadIdx.x;
  if (i >= NN * HH / 4) return;
  f32x4 s = {0.f, 0.f, 0.f, 0.f};
  for (int k = 0; k < splitk; ++k)
    s += *(const f32x4*)(part + (size_t)k * NN * HH + (size_t)i * 4);
  bf16x4 o = __builtin_convertvector(s, bf16x4);
  *(bf16x4*)(out + (size_t)i * 4) = o;
}

// ---------------- normalized aggregation: out = relu(dinv_d*(sum dinv_s*in[s] + dinv_d*in[d]) + b)
// one wave per dst node, lane = 4 features, readlane-broadcast src -> coalesced 512B row gathers
__global__ __launch_bounds__(256)
void k_agg(const u16* __restrict__ in, const int* __restrict__ offs, const int* __restrict__ csr,
           const float* __restrict__ dinv, const float* __restrict__ bias, u16* __restrict__ out)
{
  int d = (blockIdx.x << 2) + (threadIdx.x >> 6);
  int lane = threadIdx.x & 63;
  int f0 = lane << 2;
  float di = dinv[d];

  bf16x4 hs = *(const bf16x4*)(in + (size_t)d * 256 + f0);
  f32x4 acc = di * __builtin_convertvector(hs, f32x4);   // self-loop term

  int beg = offs[d], end = offs[d + 1];
  for (int e = beg; e < end; e += 64) {
    int cnt = end - e; if (cnt > 64) cnt = 64;
    int sv = 0; float wv = 0.f;
    if (lane < cnt) { sv = csr[e + lane]; wv = dinv[sv]; }
    int j = 0;
    for (; j + 4 <= cnt; j += 4) {
      int s0 = __builtin_amdgcn_readlane(sv, j);
      int s1 = __builtin_amdgcn_readlane(sv, j + 1);
      int s2 = __builtin_amdgcn_readlane(sv, j + 2);
      int s3 = __builtin_amdgcn_readlane(sv, j + 3);
      float w0 = __builtin_bit_cast(float, __builtin_amdgcn_readlane(__builtin_bit_cast(int, wv), j));
      float w1 = __builtin_bit_cast(float, __builtin_amdgcn_readlane(__builtin_bit_cast(int, wv), j + 1));
      float w2 = __builtin_bit_cast(float, __builtin_amdgcn_readlane(__builtin_bit_cast(int, wv), j + 2));
      float w3 = __builtin_bit_cast(float, __builtin_amdgcn_readlane(__builtin_bit_cast(int, wv), j + 3));
      bf16x4 h0 = *(const bf16x4*)(in + (size_t)s0 * 256 + f0);
      bf16x4 h1 = *(const bf16x4*)(in + (size_t)s1 * 256 + f0);
      bf16x4 h2 = *(const bf16x4*)(in + (size_t)s2 * 256 + f0);
      bf16x4 h3 = *(const bf16x4*)(in + (size_t)s3 * 256 + f0);
      acc += w0 * __builtin_convertvector(h0, f32x4);
      acc += w1 * __builtin_convertvector(h1, f32x4);
      acc += w2 * __builtin_convertvector(h2, f32x4);
      acc += w3 * __builtin_convertvector(h3, f32x4);
    }
    for (; j < cnt; ++j) {
      int sj = __builtin_amdgcn_readlane(sv, j);
      float wj = __builtin_bit_cast(float, __builtin_amdgcn_readlane(__builtin_bit_cast(int, wv), j));
      bf16x4 hj = *(const bf16x4*)(in + (size_t)sj * 256 + f0);
      acc += wj * __builtin_convertvector(hj, f32x4);
    }
  }
  f32x4 b = *(const f32x4*)(bias + f0);
  f32x4 o = di * acc + b;
  o.x = fmaxf(o.x, 0.f); o.y = fmaxf(o.y, 0.f); o.z = fmaxf(o.z, 0.f); o.w = fmaxf(o.w, 0.f);
  bf16x4 ob = __builtin_convertvector(o, bf16x4);
  *(bf16x4*)(out + (size_t)d * 256 + f0) = ob;
}

// ---------------- per-node head dots: p = h2 . linW[0:256], q = h2 . linW[256:512]
__global__ __launch_bounds__(256)
void k_pq(const u16* __restrict__ h2, const float* __restrict__ linW,
          float* __restrict__ p, float* __restrict__ q)
{
  int n = (blockIdx.x << 2) + (threadIdx.x >> 6);
  int lane = threadIdx.x & 63;
  bf16x4 h = *(const bf16x4*)(h2 + (size_t)n * 256 + (lane << 2));
  f32x4 v = __builtin_convertvector(h, f32x4);
  f32x4 wl = *(const f32x4*)(linW + (lane << 2));
  f32x4 wh = *(const f32x4*)(linW + 256 + (lane << 2));
  float ps = v.x * wl.x + v.y * wl.y + v.z * wl.z + v.w * wl.w;
  float qs = v.x * wh.x + v.y * wh.y + v.z * wh.z + v.w * wh.w;
  for (int o = 32; o > 0; o >>= 1) {
    ps += __shfl_down(ps, o);
    qs += __shfl_down(qs, o);
  }
  if (lane == 0) { p[n] = ps; q[n] = qs; }
}

__global__ void k_edgeout(const int* __restrict__ src, const int* __restrict__ dst,
                          const float* __restrict__ p, const float* __restrict__ q,
                          const float* __restrict__ lb, float* __restrict__ out)
{
  int e = blockIdx.x * blockDim.x + threadIdx.x;
  if (e < NE) out[e] = p[src[e]] + q[dst[e]] + lb[0];
}

extern "C" void kernel_launch(void* const* d_in, const int* in_sizes, int n_in,
                              void* d_out, int out_size, void* d_ws, size_t ws_size,
                              hipStream_t stream)
{
  const float* x    = (const float*)d_in[0];
  const int*   ei   = (const int*)d_in[1];   // harness delivers integer inputs as int32
  const float* W1   = (const float*)d_in[2];
  const float* b1   = (const float*)d_in[3];
  const float* W2   = (const float*)d_in[4];
  const float* b2   = (const float*)d_in[5];
  const float* linW = (const float*)d_in[6];
  const float* linb = (const float*)d_in[7];
  float* out = (float*)d_out;

  char* ws = (char*)d_ws;
  u16*   w1sw  = (u16*)(ws + WS_W1SW);
  u16*   w2sw  = (u16*)(ws + WS_W2SW);
  u16*   h1pre = (u16*)(ws + WS_H1PRE);
  u16*   h1    = (u16*)(ws + WS_H1);
  u16*   h2pre = (u16*)(ws + WS_H2PRE);
  u16*   h2    = (u16*)(ws + WS_H2);
  int*   deg   = (int*)(ws + WS_DEG);
  int*   offs  = (int*)(ws + WS_OFFS);
  int*   curs  = (int*)(ws + WS_CURS);
  float* dinv  = (float*)(ws + WS_DINV);
  float* p     = (float*)(ws + WS_P);
  float* q     = (float*)(ws + WS_Q);
  int*   csr   = (int*)(ws + WS_CSR);
  float* part  = (float*)(ws + WS_PART);

  // split-K for GEMM1 chosen by available scratch (constant per session -> graph-safe)
  int ksh = 2, splitk = 4;
  if (ws_size < WS_PART + 4ull * (size_t)NN * HH * 4) { ksh = 1; splitk = 2; }
  if (ws_size < WS_PART + 2ull * (size_t)NN * HH * 4) { ksh = 0; splitk = 1; }

  const int* esrc = ei;
  const int* edst = ei + NE;

  k_zero<<<64, 256, 0, stream>>>(deg, NN);
  k_zero<<<64, 256, 0, stream>>>(curs, NN);
  k_hist<<<NE / 256, 256, 0, stream>>>(edst, deg);
  k_scan<<<1, 1024, 0, stream>>>(deg, offs, dinv);
  k_scatter<<<NE / 256, 256, 0, stream>>>(esrc, edst, offs, curs, csr);

  k_swizzleW<<<(NN * HH) / 256, 256, 0, stream>>>(W1, w1sw, NN);
  k_swizzleW<<<(HH * HH) / 256, 256, 0, stream>>>(W2, w2sw, HH);

  // GEMM1: h1pre = x @ W1 (bf16 MFMA, on-the-fly fp32->bf16 A conversion, split-K)
  k_gemm<128, 512, true, true><<<(NN / 128) << ksh, 512, 0, stream>>>(
      x, nullptr, w1sw, part, nullptr, NN, ksh);
  k_reduce<<<(NN * HH / 4) / 256, 256, 0, stream>>>(part, h1pre, splitk);

  k_agg<<<NN / 4, 256, 0, stream>>>(h1pre, offs, csr, dinv, b1, h1);

  // GEMM2: h2pre = h1 @ W2 (bf16 direct, no split-K)
  k_gemm<64, 256, false, false><<<NN / 64, 256, 0, stream>>>(
      nullptr, h1, w2sw, nullptr, h2pre, HH, 0);

  k_agg<<<NN / 4, 256, 0, stream>>>(h2pre, offs, csr, dinv, b2, h2);

  k_pq<<<NN / 4, 256, 0, stream>>>(h2, linW, p, q);
  k_edgeout<<<NE / 256, 256, 0, stream>>>(esrc, edst, p, q, linb, out);
}